// Round 3
// baseline (573.562 us; speedup 1.0000x reference)
//
#include <hip/hip_runtime.h>
#include <math.h>

// Exact GELU: x * 0.5 * (1 + erf(x / sqrt(2)))  (approximate=False in JAX ref)
__device__ __forceinline__ float gelu_f(float v) {
    return 0.5f * v * (1.0f + erff(v * 0.70710678118654752f));
}

// Layer-1 chunk: stream KN x-values (k = K0..K0+KN-1) into all 64 accumulators.
// Everything statically indexed so acc[] / xv[] live in VGPRs (rule: runtime
// indices -> scratch).  Weight addresses are wave-uniform -> s_load from K$.
template<int K0, int KN>
__device__ __forceinline__ void l1_chunk(const float* __restrict__ xp,
                                         const float* __restrict__ W1,
                                         const float* __restrict__ gamma,
                                         float* __restrict__ acc /*[64]*/)
{
    float xv[KN];
    #pragma unroll
    for (int kk = 0; kk < KN; ++kk) {
        float v = xp[K0 + kk];
        if ((K0 + kk) >= 3 && (K0 + kk) < 23) v *= gamma[K0 + kk];  // folds at compile time
        xv[kk] = v;
    }
    #pragma unroll
    for (int o = 0; o < 64; ++o) {
        const float* w = W1 + o * 73 + K0;
        #pragma unroll
        for (int kk = 0; kk < KN; ++kk)
            acc[o] = fmaf(xv[kk], w[kk], acc[o]);
    }
}

// Round-2 lesson: peak live set must stay under the 128-VGPR tier or the
// compiler spills (VGPR=128 + 36MB scratch traffic, VALUBusy 51%).  This
// structure peaks at ~96 live floats: layer1 = acc[64]+xv[8], layer2 =
// h1[64]+h2[32].  (256,4) pins the 128-VGPR / 4-waves-per-SIMD tier.
__global__ __launch_bounds__(256, 4) void mlp_fused_kernel(
    const float* __restrict__ x,
    const float* __restrict__ alpha,
    const float* __restrict__ beta,
    const float* __restrict__ gamma,
    const float* __restrict__ g,
    const float* __restrict__ W1, const float* __restrict__ b1,
    const float* __restrict__ W2, const float* __restrict__ b2,
    const float* __restrict__ Wres, const float* __restrict__ bres,
    const float* __restrict__ W6, const float* __restrict__ b6,
    float* __restrict__ out, int B)
{
    int row = blockIdx.x * blockDim.x + threadIdx.x;
    if (row >= B) return;

    const float* xp = x + (size_t)row * 73;

    // Embed gathers issued first; their FMAs applied at the END of layer 1
    // so the ~500-cycle gather latency hides under ~4.6K FMAs.
    float x0 = xp[0];
    float x1 = xp[1];
    float xa = alpha[(int)x0];
    float xb = beta[(int)x1];

    // ---- layer 1: 73 -> 64 (k-chunked) ----
    float acc[64];
    #pragma unroll
    for (int o = 0; o < 64; ++o) acc[o] = b1[o];

    l1_chunk< 2, 8>(xp, W1, gamma, acc);
    l1_chunk<10, 8>(xp, W1, gamma, acc);
    l1_chunk<18, 8>(xp, W1, gamma, acc);
    l1_chunk<26, 8>(xp, W1, gamma, acc);
    l1_chunk<34, 8>(xp, W1, gamma, acc);
    l1_chunk<42, 8>(xp, W1, gamma, acc);
    l1_chunk<50, 8>(xp, W1, gamma, acc);
    l1_chunk<58, 8>(xp, W1, gamma, acc);
    l1_chunk<66, 7>(xp, W1, gamma, acc);

    // embed columns 0/1 (gathered values), then GELU
    #pragma unroll
    for (int o = 0; o < 64; ++o) {
        float a = fmaf(xb, W1[o * 73 + 1], acc[o]);
        a = fmaf(xa, W1[o * 73 + 0], a);
        acc[o] = gelu_f(a);
    }

    // ---- layer 2: 64 -> 32, GELU ----
    float h2[32];
    #pragma unroll
    for (int o = 0; o < 32; ++o) {
        float a = b2[o];
        const float* w = W2 + o * 64;
        #pragma unroll
        for (int k = 0; k < 64; ++k) a = fmaf(acc[k], w[k], a);
        h2[o] = gelu_f(a);
    }

    // ---- residual layer: 32 -> 32, pre-act = h2@Wres^T + bres + h2, GELU ----
    float h3[32];
    #pragma unroll
    for (int o = 0; o < 32; ++o) {
        float a = bres[o] + h2[o];
        const float* w = Wres + o * 32;
        #pragma unroll
        for (int k = 0; k < 32; ++k) a = fmaf(h2[k], w[k], a);
        h3[o] = gelu_f(a);
    }

    // ---- output: 32 -> 1 ----
    float r = b6[0] + g[0];
    #pragma unroll
    for (int k = 0; k < 32; ++k) r = fmaf(h3[k], W6[k], r);
    out[row] = r;
}

extern "C" void kernel_launch(void* const* d_in, const int* in_sizes, int n_in,
                              void* d_out, int out_size, void* d_ws, size_t ws_size,
                              hipStream_t stream) {
    const float* x     = (const float*)d_in[0];
    const float* alpha = (const float*)d_in[1];
    const float* beta  = (const float*)d_in[2];
    const float* gamma = (const float*)d_in[3];
    const float* g     = (const float*)d_in[4];
    const float* W1    = (const float*)d_in[5];
    const float* b1    = (const float*)d_in[6];
    const float* W2    = (const float*)d_in[7];
    const float* b2    = (const float*)d_in[8];
    const float* Wres  = (const float*)d_in[9];
    const float* bres  = (const float*)d_in[10];
    const float* W6    = (const float*)d_in[11];
    const float* b6    = (const float*)d_in[12];
    float* out = (float*)d_out;

    int B = out_size;  // one output per row
    int block = 256;
    int grid = (B + block - 1) / block;
    mlp_fused_kernel<<<grid, block, 0, stream>>>(x, alpha, beta, gamma, g,
                                                 W1, b1, W2, b2, Wres, bres,
                                                 W6, b6, out, B);
}

// Round 4
// 148.711 us; speedup vs baseline: 3.8569x; 3.8569x over previous
//
#include <hip/hip_runtime.h>
#include <math.h>

typedef _Float16 half8 __attribute__((ext_vector_type(8)));
typedef float f32x4 __attribute__((ext_vector_type(4)));

// Exact GELU: x * 0.5 * (1 + erf(x/sqrt(2)))  (approximate=False in JAX ref)
__device__ __forceinline__ float gelu_f(float v) {
    return 0.5f * v * (1.0f + erff(v * 0.70710678118654752f));
}

#define MFMA16(A, B, C) __builtin_amdgcn_mfma_f32_16x16x32_f16((A), (B), (C), 0, 0, 0)

// One wave owns a 16-row tile end-to-end.  fp16 MFMA, fp32 accum.
// A-frag: row = lane&15, k = 32*s + 8*(lane>>4) + j  (A/B use the SAME k map,
// so only consistency matters).  C-layout (m89-verified): col = lane&15,
// row = 4*(lane>>4) + reg.  Weights hoisted to VGPRs once per wave; layer
// transitions via per-wave LDS (wave-local -> lgkmcnt only, no barriers).
// Round-3 lesson: don't force 128-VGPR tier; (256,3) caps at ~168 vs ~150 est.
__global__ __launch_bounds__(256, 3) void mlp_mfma_kernel(
    const float* __restrict__ x,
    const float* __restrict__ alpha,
    const float* __restrict__ beta,
    const float* __restrict__ gamma,
    const float* __restrict__ gscal,
    const float* __restrict__ W1, const float* __restrict__ b1,
    const float* __restrict__ W2, const float* __restrict__ b2,
    const float* __restrict__ Wres, const float* __restrict__ bres,
    const float* __restrict__ W6, const float* __restrict__ b6,
    float* __restrict__ out, int B)
{
    const int lane = threadIdx.x & 63;
    const int wid  = threadIdx.x >> 6;
    const int c    = lane & 15;   // col (N) index / A-row index
    const int g    = lane >> 4;   // k-group 0..3

    // per-wave LDS staging for activation re-layout (no cross-wave sharing)
    __shared__ __align__(16) _Float16 h1buf[4][16 * 80]; // 16 rows x 64 (+pad to 80)
    __shared__ __align__(16) _Float16 h2buf[4][16 * 40]; // 16 rows x 32 (+pad to 40)
    _Float16* __restrict__ h1b = h1buf[wid];
    _Float16* __restrict__ h2b = h2buf[wid];

    // ---- hoisted weight fragments (per-lane; L2-resident re-reads) ----
    // W1: [64,73], B-frag b[j] = W1[n][k], n = 16t+c, k = 32s+8g+j (zero-pad k>=73)
    half8 w1f[4][3];
    #pragma unroll
    for (int t = 0; t < 4; ++t) {
        #pragma unroll
        for (int s = 0; s < 3; ++s) {
            #pragma unroll
            for (int j = 0; j < 8; ++j) {
                int k  = 32 * s + 8 * g + j;
                int kc = k < 73 ? k : 72;           // clamp: no speculative OOB load
                float v = W1[(16 * t + c) * 73 + kc];
                w1f[t][s][j] = (k < 73) ? (_Float16)v : (_Float16)0.f;
            }
        }
    }
    // W2: [32,64]
    half8 w2f[2][2];
    #pragma unroll
    for (int t = 0; t < 2; ++t)
        #pragma unroll
        for (int s = 0; s < 2; ++s)
            #pragma unroll
            for (int j = 0; j < 8; ++j)
                w2f[t][s][j] = (_Float16)W2[(16 * t + c) * 64 + 32 * s + 8 * g + j];
    // Wres: [32,32]
    half8 wrf[2];
    #pragma unroll
    for (int t = 0; t < 2; ++t)
        #pragma unroll
        for (int j = 0; j < 8; ++j)
            wrf[t][j] = (_Float16)Wres[(16 * t + c) * 32 + 8 * g + j];

    // gamma multipliers for k-step 0 (k = 8g+j; scale cols 3..22 only)
    float gm[8];
    #pragma unroll
    for (int j = 0; j < 8; ++j) {
        int k  = 8 * g + j;
        int kc = k < 3 ? 3 : (k > 22 ? 22 : k);     // clamp: safe load
        float gv = gamma[kc];
        gm[j] = (k >= 3 && k < 23) ? gv : 1.0f;
    }

    float b1f[4], b2f[2], brf[2], w6f[2];
    #pragma unroll
    for (int t = 0; t < 4; ++t) b1f[t] = b1[16 * t + c];
    #pragma unroll
    for (int t = 0; t < 2; ++t) { b2f[t] = b2[16 * t + c]; brf[t] = bres[16 * t + c]; w6f[t] = W6[16 * t + c]; }
    const float b6g = b6[0] + gscal[0];

    // ---- grid-stride over 16-row tiles (B = 1M divisible by 16) ----
    const int ntiles = B >> 4;
    const int totw   = gridDim.x * 4;
    for (int tile = blockIdx.x * 4 + wid; tile < ntiles; tile += totw) {
        const int R0 = tile << 4;
        const float* __restrict__ xr = x + (size_t)(R0 + c) * 73;

        // x loads for this lane's k-chunks (issued up front)
        float xv0[8], xv1[8], xv2[8];
        #pragma unroll
        for (int j = 0; j < 8; ++j) xv0[j] = xr[8 * g + j];
        #pragma unroll
        for (int j = 0; j < 8; ++j) xv1[j] = xr[32 + 8 * g + j];
        #pragma unroll
        for (int j = 0; j < 8; ++j) {
            int k = 64 + 8 * g + j;
            float v = xr[k < 73 ? k : 72];
            xv2[j] = (k < 73) ? v : 0.f;
        }

        // embed gathers (only g==0 lanes own cols 0/1); dependent chain,
        // consumed by the LAST k-step's MFMAs
        float xa = 0.f, xb = 0.f;
        if (g == 0) {
            xa = alpha[(int)xv0[0]];
            xb = beta[(int)xv0[1]];
        }

        // ---- layer 1: 73->64.  k-steps 1,2 first (no gather dep) ----
        half8 a1, a2;
        #pragma unroll
        for (int j = 0; j < 8; ++j) a1[j] = (_Float16)xv1[j];
        #pragma unroll
        for (int j = 0; j < 8; ++j) a2[j] = (_Float16)xv2[j];

        f32x4 acc[4];
        #pragma unroll
        for (int t = 0; t < 4; ++t) { f32x4 z = { b1f[t], b1f[t], b1f[t], b1f[t] }; acc[t] = z; }
        #pragma unroll
        for (int t = 0; t < 4; ++t) acc[t] = MFMA16(a1, w1f[t][1], acc[t]);
        #pragma unroll
        for (int t = 0; t < 4; ++t) acc[t] = MFMA16(a2, w1f[t][2], acc[t]);

        half8 a0;
        #pragma unroll
        for (int j = 0; j < 8; ++j) {
            float v = xv0[j] * gm[j];
            if (j == 0) { if (g == 0) v = xa; }
            if (j == 1) { if (g == 0) v = xb; }
            a0[j] = (_Float16)v;
        }
        #pragma unroll
        for (int t = 0; t < 4; ++t) acc[t] = MFMA16(a0, w1f[t][0], acc[t]);

        // GELU -> h1 to LDS (row = 4g+r, col = 16t+c, stride 80)
        #pragma unroll
        for (int t = 0; t < 4; ++t)
            #pragma unroll
            for (int r = 0; r < 4; ++r)
                h1b[(4 * g + r) * 80 + 16 * t + c] = (_Float16)gelu_f(acc[t][r]);

        asm volatile("s_waitcnt lgkmcnt(0)" ::: "memory");

        // ---- layer 2: 64->32 ----
        half8 a2f0 = *reinterpret_cast<const half8*>(&h1b[c * 80 + 8 * g]);
        half8 a2f1 = *reinterpret_cast<const half8*>(&h1b[c * 80 + 32 + 8 * g]);
        f32x4 ac2[2];
        #pragma unroll
        for (int t = 0; t < 2; ++t) {
            f32x4 z = { b2f[t], b2f[t], b2f[t], b2f[t] };
            z = MFMA16(a2f0, w2f[t][0], z);
            ac2[t] = MFMA16(a2f1, w2f[t][1], z);
        }
        float h2c[2][4];
        #pragma unroll
        for (int t = 0; t < 2; ++t)
            #pragma unroll
            for (int r = 0; r < 4; ++r)
                h2c[t][r] = gelu_f(ac2[t][r]);

        // h2 to LDS (stride 40)
        #pragma unroll
        for (int t = 0; t < 2; ++t)
            #pragma unroll
            for (int r = 0; r < 4; ++r)
                h2b[(4 * g + r) * 40 + 16 * t + c] = (_Float16)h2c[t][r];

        asm volatile("s_waitcnt lgkmcnt(0)" ::: "memory");

        // ---- residual layer: C-init = bres + h2 (matching C-layout slots) ----
        half8 arf = *reinterpret_cast<const half8*>(&h2b[c * 40 + 8 * g]);
        f32x4 acr[2];
        #pragma unroll
        for (int t = 0; t < 2; ++t) {
            f32x4 z = { brf[t] + h2c[t][0], brf[t] + h2c[t][1],
                        brf[t] + h2c[t][2], brf[t] + h2c[t][3] };
            acr[t] = MFMA16(arf, wrf[t], z);
        }

        // ---- final 32->1: per-lane partial, butterfly-reduce over c ----
        f32x4 p;
        #pragma unroll
        for (int r = 0; r < 4; ++r)
            p[r] = gelu_f(acr[0][r]) * w6f[0] + gelu_f(acr[1][r]) * w6f[1];
        #pragma unroll
        for (int m = 1; m < 16; m <<= 1) {
            #pragma unroll
            for (int r = 0; r < 4; ++r) p[r] += __shfl_xor(p[r], m, 64);
        }
        if (c == 0) {
            f32x4 o = { p[0] + b6g, p[1] + b6g, p[2] + b6g, p[3] + b6g };
            *reinterpret_cast<f32x4*>(out + R0 + 4 * g) = o;  // rows R0+4g..+3
        }
    }
}

extern "C" void kernel_launch(void* const* d_in, const int* in_sizes, int n_in,
                              void* d_out, int out_size, void* d_ws, size_t ws_size,
                              hipStream_t stream) {
    const float* x     = (const float*)d_in[0];
    const float* alpha = (const float*)d_in[1];
    const float* beta  = (const float*)d_in[2];
    const float* gamma = (const float*)d_in[3];
    const float* g     = (const float*)d_in[4];
    const float* W1    = (const float*)d_in[5];
    const float* b1    = (const float*)d_in[6];
    const float* W2    = (const float*)d_in[7];
    const float* b2    = (const float*)d_in[8];
    const float* Wres  = (const float*)d_in[9];
    const float* bres  = (const float*)d_in[10];
    const float* W6    = (const float*)d_in[11];
    const float* b6    = (const float*)d_in[12];
    float* out = (float*)d_out;

    int B = out_size;          // 1e6 rows; divisible by 16
    int nblocks = 1536;        // 4 waves/block; grid-stride over 65536 tiles
    mlp_mfma_kernel<<<nblocks, 256, 0, stream>>>(x, alpha, beta, gamma, g,
                                                 W1, b1, W2, b2, Wres, bres,
                                                 W6, b6, out, B);
}

// Round 6
// 125.211 us; speedup vs baseline: 4.5808x; 1.1877x over previous
//
#include <hip/hip_runtime.h>
#include <math.h>

typedef _Float16 half8 __attribute__((ext_vector_type(8)));
typedef __fp16   fp16x2 __attribute__((ext_vector_type(2)));  // cvt_pkrtz's return type
typedef float f32x4 __attribute__((ext_vector_type(4)));

// Branchless exact-grade GELU: x*0.5*(1+erf(x/sqrt(2))) with A&S 7.1.26 erf,
// |erf err| <= 1.5e-7 (vs output threshold 2.47e-2).  ~15 VALU + rcp + exp2,
// no divergence.  Round-4 lesson: ocml erff's two-path branch made GELU the
// dominant VALU cost (32 gelu/lane/tile, VALUBusy 41% at only 4% MfmaUtil).
__device__ __forceinline__ float gelu_f(float v) {
    float y  = v * 0.70710678118654752f;
    float ay = __builtin_fabsf(y);
    float t  = __builtin_amdgcn_rcpf(__builtin_fmaf(0.3275911f, ay, 1.0f));
    float p  = __builtin_fmaf(t, 1.061405429f, -1.453152027f);
    p = __builtin_fmaf(p, t, 1.421413741f);
    p = __builtin_fmaf(p, t, -0.284496736f);
    p = __builtin_fmaf(p, t, 0.254829592f);
    p = p * t;
    float e  = __builtin_amdgcn_exp2f(ay * ay * -1.4426950408889634f);
    float er = __builtin_fmaf(-p, e, 1.0f);        // erf(|y|), saturates to 1
    er = __builtin_copysignf(er, v);               // restore sign
    float hv = 0.5f * v;
    return __builtin_fmaf(hv, er, hv);
}

#define MFMA16(A, B, C) __builtin_amdgcn_mfma_f32_16x16x32_f16((A), (B), (C), 0, 0, 0)

// One wave owns a 16-row tile end-to-end.  fp16 MFMA, fp32 accum.
// A-frag: row = lane&15, k = 32*s + 8*(lane>>4) + j (A/B consistent k-map).
// C-layout (m89): col = lane&15, row = 4*(lane>>4) + reg.
// h1 LDS stride 72 halves: 144B rows stay 16B-aligned for ds_read_b128 while
// splitting the 4 g-groups across 2 bank-sets (4-way write conflict vs 8-way
// at stride 80).
__global__ __launch_bounds__(256, 3) void mlp_mfma_kernel(
    const float* __restrict__ x,
    const float* __restrict__ alpha,
    const float* __restrict__ beta,
    const float* __restrict__ gamma,
    const float* __restrict__ gscal,
    const float* __restrict__ W1, const float* __restrict__ b1,
    const float* __restrict__ W2, const float* __restrict__ b2,
    const float* __restrict__ Wres, const float* __restrict__ bres,
    const float* __restrict__ W6, const float* __restrict__ b6,
    float* __restrict__ out, int B)
{
    const int lane = threadIdx.x & 63;
    const int wid  = threadIdx.x >> 6;
    const int c    = lane & 15;   // col (N) index / A-row index
    const int g    = lane >> 4;   // k-group 0..3

    // per-wave LDS staging for activation re-layout (no cross-wave sharing)
    __shared__ __align__(16) _Float16 h1buf[4][16 * 72]; // 16 rows x 64 (+pad to 72)
    __shared__ __align__(16) _Float16 h2buf[4][16 * 40]; // 16 rows x 32 (+pad to 40)
    _Float16* __restrict__ h1b = h1buf[wid];
    _Float16* __restrict__ h2b = h2buf[wid];

    // gamma multipliers for k-step 0 (k = 8g+j; scale cols 3..22 only)
    float gm[8];
    #pragma unroll
    for (int j = 0; j < 8; ++j) {
        int k  = 8 * g + j;
        int kc = k < 3 ? 3 : (k > 22 ? 22 : k);     // clamp: safe load
        float gv = gamma[kc];
        gm[j] = (k >= 3 && k < 23) ? gv : 1.0f;
    }

    // ---- hoisted weight fragments (per-lane; L2-resident re-reads) ----
    // W1: [64,73], B-frag b[j] = W1[n][k], n = 16t+c, k = 32s+8g+j (zero-pad
    // k>=73).  gamma folded into the s=0 fragment (k=8g+j is this lane's k).
    half8 w1f[4][3];
    #pragma unroll
    for (int t = 0; t < 4; ++t) {
        #pragma unroll
        for (int s = 0; s < 3; ++s) {
            #pragma unroll
            for (int j = 0; j < 8; ++j) {
                int k  = 32 * s + 8 * g + j;
                int kc = k < 73 ? k : 72;           // clamp: no OOB load
                float v = W1[(16 * t + c) * 73 + kc];
                if (s == 0) v *= gm[j];
                w1f[t][s][j] = (k < 73) ? (_Float16)v : (_Float16)0.f;
            }
        }
    }
    // W2: [32,64]
    half8 w2f[2][2];
    #pragma unroll
    for (int t = 0; t < 2; ++t)
        #pragma unroll
        for (int s = 0; s < 2; ++s)
            #pragma unroll
            for (int j = 0; j < 8; ++j)
                w2f[t][s][j] = (_Float16)W2[(16 * t + c) * 64 + 32 * s + 8 * g + j];
    // Wres: [32,32]
    half8 wrf[2];
    #pragma unroll
    for (int t = 0; t < 2; ++t)
        #pragma unroll
        for (int j = 0; j < 8; ++j)
            wrf[t][j] = (_Float16)Wres[(16 * t + c) * 32 + 8 * g + j];

    float b1f[4], b2f[2], brf[2], w6f[2];
    #pragma unroll
    for (int t = 0; t < 4; ++t) b1f[t] = b1[16 * t + c];
    #pragma unroll
    for (int t = 0; t < 2; ++t) { b2f[t] = b2[16 * t + c]; brf[t] = bres[16 * t + c]; w6f[t] = W6[16 * t + c]; }
    const float b6g = b6[0] + gscal[0];

    // ---- grid-stride over 16-row tiles (B = 1M divisible by 16) ----
    const int ntiles = B >> 4;
    const int totw   = gridDim.x * 4;
    for (int tile = blockIdx.x * 4 + wid; tile < ntiles; tile += totw) {
        const int R0 = tile << 4;
        const float* __restrict__ xr = x + (size_t)(R0 + c) * 73;

        // x loads for this lane's k-chunks (issued up front)
        float xv0[8], xv1[8], xv2[8];
        #pragma unroll
        for (int j = 0; j < 8; ++j) xv0[j] = xr[8 * g + j];
        #pragma unroll
        for (int j = 0; j < 8; ++j) xv1[j] = xr[32 + 8 * g + j];
        #pragma unroll
        for (int j = 0; j < 8; ++j) {
            int k = 64 + 8 * g + j;
            float v = xr[k < 73 ? k : 72];
            xv2[j] = (k < 73) ? v : 0.f;
        }

        // embed gathers (only g==0 lanes own cols 0/1); dependent chain,
        // consumed by the LAST k-step's MFMAs
        float xa = 0.f, xb = 0.f;
        if (g == 0) {
            xa = alpha[(int)xv0[0]];
            xb = beta[(int)xv0[1]];
        }

        // ---- layer 1: 73->64.  k-steps 1,2 first (no gather dep) ----
        union H8 { half8 h8; fp16x2 h2[4]; };
        H8 a1u, a2u;
        #pragma unroll
        for (int j = 0; j < 4; ++j) {
            a1u.h2[j] = __builtin_amdgcn_cvt_pkrtz(xv1[2 * j], xv1[2 * j + 1]);
            a2u.h2[j] = __builtin_amdgcn_cvt_pkrtz(xv2[2 * j], xv2[2 * j + 1]);
        }

        f32x4 acc[4];
        #pragma unroll
        for (int t = 0; t < 4; ++t) { f32x4 z = { b1f[t], b1f[t], b1f[t], b1f[t] }; acc[t] = z; }
        #pragma unroll
        for (int t = 0; t < 4; ++t) acc[t] = MFMA16(a1u.h8, w1f[t][1], acc[t]);
        #pragma unroll
        for (int t = 0; t < 4; ++t) acc[t] = MFMA16(a2u.h8, w1f[t][2], acc[t]);

        // k-step 0: gamma already folded into w1f[t][0]; cols 0/1 replaced by
        // gathered embeds on g==0 lanes
        H8 a0u;
        #pragma unroll
        for (int j = 0; j < 4; ++j)
            a0u.h2[j] = __builtin_amdgcn_cvt_pkrtz(xv0[2 * j], xv0[2 * j + 1]);
        {
            fp16x2 we = __builtin_amdgcn_cvt_pkrtz(xa, xb);
            if (g == 0) a0u.h2[0] = we;
        }
        #pragma unroll
        for (int t = 0; t < 4; ++t) acc[t] = MFMA16(a0u.h8, w1f[t][0], acc[t]);

        // GELU -> h1 to LDS (row = 4g+r, col = 16t+c, stride 72)
        #pragma unroll
        for (int t = 0; t < 4; ++t)
            #pragma unroll
            for (int r = 0; r < 4; ++r)
                h1b[(4 * g + r) * 72 + 16 * t + c] = (_Float16)gelu_f(acc[t][r]);

        asm volatile("s_waitcnt lgkmcnt(0)" ::: "memory");

        // ---- layer 2: 64->32 ----
        half8 a2f0 = *reinterpret_cast<const half8*>(&h1b[c * 72 + 8 * g]);
        half8 a2f1 = *reinterpret_cast<const half8*>(&h1b[c * 72 + 32 + 8 * g]);
        f32x4 ac2[2];
        #pragma unroll
        for (int t = 0; t < 2; ++t) {
            f32x4 z = { b2f[t], b2f[t], b2f[t], b2f[t] };
            z = MFMA16(a2f0, w2f[t][0], z);
            ac2[t] = MFMA16(a2f1, w2f[t][1], z);
        }
        float h2c[2][4];
        #pragma unroll
        for (int t = 0; t < 2; ++t)
            #pragma unroll
            for (int r = 0; r < 4; ++r)
                h2c[t][r] = gelu_f(ac2[t][r]);

        // h2 to LDS (stride 40)
        #pragma unroll
        for (int t = 0; t < 2; ++t)
            #pragma unroll
            for (int r = 0; r < 4; ++r)
                h2b[(4 * g + r) * 40 + 16 * t + c] = (_Float16)h2c[t][r];

        asm volatile("s_waitcnt lgkmcnt(0)" ::: "memory");

        // ---- residual layer: C-init = bres + h2 (matching C-layout slots) ----
        half8 arf = *reinterpret_cast<const half8*>(&h2b[c * 40 + 8 * g]);
        f32x4 acr[2];
        #pragma unroll
        for (int t = 0; t < 2; ++t) {
            f32x4 z = { brf[t] + h2c[t][0], brf[t] + h2c[t][1],
                        brf[t] + h2c[t][2], brf[t] + h2c[t][3] };
            acr[t] = MFMA16(arf, wrf[t], z);
        }

        // ---- final 32->1: per-lane partial, butterfly-reduce over c ----
        f32x4 p;
        #pragma unroll
        for (int r = 0; r < 4; ++r)
            p[r] = gelu_f(acr[0][r]) * w6f[0] + gelu_f(acr[1][r]) * w6f[1];
        #pragma unroll
        for (int m = 1; m < 16; m <<= 1) {
            #pragma unroll
            for (int r = 0; r < 4; ++r) p[r] += __shfl_xor(p[r], m, 64);
        }
        if (c == 0) {
            f32x4 o = { p[0] + b6g, p[1] + b6g, p[2] + b6g, p[3] + b6g };
            *reinterpret_cast<f32x4*>(out + R0 + 4 * g) = o;  // rows R0+4g..+3
        }
    }
}

extern "C" void kernel_launch(void* const* d_in, const int* in_sizes, int n_in,
                              void* d_out, int out_size, void* d_ws, size_t ws_size,
                              hipStream_t stream) {
    const float* x     = (const float*)d_in[0];
    const float* alpha = (const float*)d_in[1];
    const float* beta  = (const float*)d_in[2];
    const float* gamma = (const float*)d_in[3];
    const float* g     = (const float*)d_in[4];
    const float* W1    = (const float*)d_in[5];
    const float* b1    = (const float*)d_in[6];
    const float* W2    = (const float*)d_in[7];
    const float* b2    = (const float*)d_in[8];
    const float* Wres  = (const float*)d_in[9];
    const float* bres  = (const float*)d_in[10];
    const float* W6    = (const float*)d_in[11];
    const float* b6    = (const float*)d_in[12];
    float* out = (float*)d_out;

    int B = out_size;          // 1e6 rows; divisible by 16
    int nblocks = 1536;        // 4 waves/block; grid-stride over 65536 tiles
    mlp_mfma_kernel<<<nblocks, 256, 0, stream>>>(x, alpha, beta, gamma, g,
                                                 W1, b1, W2, b2, Wres, bres,
                                                 W6, b6, out, B);
}